// Round 1
// baseline (297.762 us; speedup 1.0000x reference)
//
#include <hip/hip_runtime.h>
#include <hip/hip_bf16.h>

#define B_ 16
#define C_ 256
#define N_ 4096
#define CN_ (C_ * N_)   // 1048576

typedef __attribute__((ext_vector_type(8))) short bf16x8_t;
typedef __attribute__((ext_vector_type(4))) float f32x4_t;

__device__ __forceinline__ unsigned short f2bf(float f) {
    __hip_bfloat16 h = __float2bfloat16(f);
    return __builtin_bit_cast(unsigned short, h);
}
__device__ __forceinline__ float bf2f(unsigned short u) {
    return __builtin_bit_cast(float, (unsigned int)u << 16);
}

// -------------------- kernel 1: norms + bf16 normalize --------------------
__global__ __launch_bounds__(256) void knorm(const float* __restrict__ x1,
                                             const float* __restrict__ x2,
                                             unsigned short* __restrict__ x1n,
                                             unsigned short* __restrict__ x2n,
                                             float* __restrict__ norms) {
    int row = blockIdx.x;              // b*256 + c
    int t = threadIdx.x;
    const float4* r1 = (const float4*)(x1 + (size_t)row * N_);
    const float4* r2 = (const float4*)(x2 + (size_t)row * N_);
    float4 a[4], b[4];
    float s1 = 0.f, s2 = 0.f;
#pragma unroll
    for (int p = 0; p < 4; ++p) {
        a[p] = r1[p * 256 + t];
        b[p] = r2[p * 256 + t];
        s1 += a[p].x * a[p].x + a[p].y * a[p].y + a[p].z * a[p].z + a[p].w * a[p].w;
        s2 += b[p].x * b[p].x + b[p].y * b[p].y + b[p].z * b[p].z + b[p].w * b[p].w;
    }
#pragma unroll
    for (int m = 32; m; m >>= 1) { s1 += __shfl_xor(s1, m); s2 += __shfl_xor(s2, m); }
    __shared__ float red[2][4];
    int wid = t >> 6;
    if ((t & 63) == 0) { red[0][wid] = s1; red[1][wid] = s2; }
    __syncthreads();
    s1 = red[0][0] + red[0][1] + red[0][2] + red[0][3];
    s2 = red[1][0] + red[1][1] + red[1][2] + red[1][3];
    float n1 = fmaxf(sqrtf(s1), 1e-12f);
    float n2 = fmaxf(sqrtf(s2), 1e-12f);
    if (t == 0) {
        int bb = row >> 8, cc = row & 255;
        norms[(bb * 2 + 0) * 256 + cc] = n1;
        norms[(bb * 2 + 1) * 256 + cc] = n2;
    }
    float i1 = 1.0f / n1, i2 = 1.0f / n2;
    unsigned short* o1 = x1n + (size_t)row * N_;
    unsigned short* o2 = x2n + (size_t)row * N_;
#pragma unroll
    for (int p = 0; p < 4; ++p) {
        ushort4 w1, w2;
        w1.x = f2bf(a[p].x * i1); w1.y = f2bf(a[p].y * i1);
        w1.z = f2bf(a[p].z * i1); w1.w = f2bf(a[p].w * i1);
        w2.x = f2bf(b[p].x * i2); w2.y = f2bf(b[p].y * i2);
        w2.z = f2bf(b[p].z * i2); w2.w = f2bf(b[p].w * i2);
        *(ushort4*)(o1 + (size_t)(p * 256 + t) * 4) = w1;
        *(ushort4*)(o2 + (size_t)(p * 256 + t) * 4) = w2;
    }
}

// ---------------- kernel 2: logits = (x1n+x2n) @ xwn^T --------------------
__device__ __forceinline__ uint4 bf16x8_add(uint4 a, uint4 b) {
    const unsigned short* pa = (const unsigned short*)&a;
    const unsigned short* pb = (const unsigned short*)&b;
    uint4 res;
    unsigned short* pr = (unsigned short*)&res;
#pragma unroll
    for (int i = 0; i < 8; ++i) pr[i] = f2bf(bf2f(pa[i]) + bf2f(pb[i]));
    return res;
}

__global__ __launch_bounds__(256) void klogits(const unsigned short* __restrict__ x1n,
                                               const unsigned short* __restrict__ x2n,
                                               float* __restrict__ logits) {
    int bid = blockIdx.x;                 // 512 blocks
    int xcd = bid & 7;
    int u = bid >> 3;                     // 0..63
    int b = xcd + 8 * (u & 1);
    int tw = u >> 1;                      // 0..31
    int w = tw & 1;
    int tile = tw >> 1;                   // 0..15
    int c0 = (tile & 3) * 64;
    int d0 = (tile >> 2) * 64;

    const unsigned short* A1 = x1n + (size_t)b * CN_;
    const unsigned short* A2 = x2n + (size_t)b * CN_;
    const unsigned short* Bp = (w ? x2n : x1n) + (size_t)b * CN_;

    __shared__ unsigned short sA[64][72];
    __shared__ unsigned short sB[64][72];

    int t = threadIdx.x, lane = t & 63, wid = t >> 6;
    int wc = wid >> 1, wd = wid & 1;

    f32x4_t acc[2][2];
#pragma unroll
    for (int i = 0; i < 2; ++i)
#pragma unroll
        for (int j = 0; j < 2; ++j) acc[i][j] = 0.f;

    int srow = t >> 3, scol = (t & 7) * 8;

    for (int ks = 0; ks < 64; ++ks) {
        int k0 = ks * 64;
#pragma unroll
        for (int p = 0; p < 2; ++p) {
            int r = srow + p * 32;
            uint4 va = *(const uint4*)(A1 + (size_t)(c0 + r) * N_ + k0 + scol);
            uint4 vb = *(const uint4*)(A2 + (size_t)(c0 + r) * N_ + k0 + scol);
            *(uint4*)&sA[r][scol] = bf16x8_add(va, vb);
            uint4 vB = *(const uint4*)(Bp + (size_t)(d0 + r) * N_ + k0 + scol);
            *(uint4*)&sB[r][scol] = vB;
        }
        __syncthreads();
#pragma unroll
        for (int ksub = 0; ksub < 2; ++ksub) {
            int kc = ksub * 32 + (lane >> 4) * 8;
            bf16x8_t a0 = *(const bf16x8_t*)&sA[wc * 32 + (lane & 15)][kc];
            bf16x8_t a1 = *(const bf16x8_t*)&sA[wc * 32 + 16 + (lane & 15)][kc];
            bf16x8_t b0 = *(const bf16x8_t*)&sB[wd * 32 + (lane & 15)][kc];
            bf16x8_t b1 = *(const bf16x8_t*)&sB[wd * 32 + 16 + (lane & 15)][kc];
            acc[0][0] = __builtin_amdgcn_mfma_f32_16x16x32_bf16(a0, b0, acc[0][0], 0, 0, 0);
            acc[0][1] = __builtin_amdgcn_mfma_f32_16x16x32_bf16(a0, b1, acc[0][1], 0, 0, 0);
            acc[1][0] = __builtin_amdgcn_mfma_f32_16x16x32_bf16(a1, b0, acc[1][0], 0, 0, 0);
            acc[1][1] = __builtin_amdgcn_mfma_f32_16x16x32_bf16(a1, b1, acc[1][1], 0, 0, 0);
        }
        __syncthreads();
    }

    float* outp = logits + ((size_t)((b * 2 + w) * 256 + c0 + wc * 32)) * 256 + d0 + wd * 32;
    int orow = (lane >> 4) * 4, ocol = lane & 15;
#pragma unroll
    for (int mi = 0; mi < 2; ++mi)
#pragma unroll
        for (int ni = 0; ni < 2; ++ni)
#pragma unroll
            for (int r = 0; r < 4; ++r)
                outp[(size_t)(mi * 16 + orow + r) * 256 + ni * 16 + ocol] = acc[mi][ni][r];
}

// ------------- kernel 3: row softmax + fold norm[d], emit bf16 ------------
__global__ __launch_bounds__(64) void ksoftmax(const float* __restrict__ logits,
                                               const float* __restrict__ norms,
                                               unsigned short* __restrict__ attnp) {
    int rid = blockIdx.x;               // (b*2+w)*256 + c
    int l = threadIdx.x;
    const float* row = logits + (size_t)rid * 256;
    int bw = rid >> 8;
    float v[4];
    float m = -1e30f;
#pragma unroll
    for (int j = 0; j < 4; ++j) { v[j] = row[j * 64 + l]; m = fmaxf(m, v[j]); }
#pragma unroll
    for (int s = 32; s; s >>= 1) m = fmaxf(m, __shfl_xor(m, s));
    float sum = 0.f;
#pragma unroll
    for (int j = 0; j < 4; ++j) { v[j] = __expf(v[j] - m); sum += v[j]; }
#pragma unroll
    for (int s = 32; s; s >>= 1) sum += __shfl_xor(sum, s);
    float rs = 1.0f / sum;
    unsigned short* outp = attnp + (size_t)rid * 256;
    const float* nr = norms + (size_t)bw * 256;
#pragma unroll
    for (int j = 0; j < 4; ++j)
        outp[j * 64 + l] = f2bf(v[j] * rs * nr[j * 64 + l]);
}

// ------- kernel 4: out[n,c] = yT1 + yT2 + x1 + x2 (fused both which) ------
__global__ __launch_bounds__(256) void kout(const unsigned short* __restrict__ x1n,
                                            const unsigned short* __restrict__ x2n,
                                            const unsigned short* __restrict__ attnp,
                                            const float* __restrict__ x1,
                                            const float* __restrict__ x2,
                                            float* __restrict__ out) {
    int bid = blockIdx.x;              // 2048 blocks
    int xcd = bid & 7;
    int u = bid >> 3;                  // 0..255
    int b = xcd + 8 * (u & 1);
    int rest = u >> 1;                 // 0..127
    int n0 = (rest >> 1) * 64;
    int c0 = (rest & 1) * 128;

    __shared__ unsigned short sA1[64][72];
    __shared__ unsigned short sA2[64][72];
    __shared__ unsigned short sB1[128][72];
    __shared__ unsigned short sB2[128][72];

    const unsigned short* A1 = x1n + (size_t)b * CN_;
    const unsigned short* A2 = x2n + (size_t)b * CN_;
    const unsigned short* B1 = attnp + ((size_t)(b * 2 + 0) * 256 + c0) * 256;
    const unsigned short* B2 = attnp + ((size_t)(b * 2 + 1) * 256 + c0) * 256;

    int t = threadIdx.x, lane = t & 63, wc = t >> 6;   // wave -> 32-wide c slice

    f32x4_t acc1[4][2], acc2[4][2];
#pragma unroll
    for (int i = 0; i < 4; ++i)
#pragma unroll
        for (int j = 0; j < 2; ++j) { acc1[i][j] = 0.f; acc2[i][j] = 0.f; }

    int dl = t >> 3, n8 = (t & 7) * 8;

    for (int ks = 0; ks < 4; ++ks) {
        int k0 = ks * 64;
        // stage A transposed: sA[n][d] <- xn[k0+d][n0+n]
#pragma unroll
        for (int p = 0; p < 2; ++p) {
            int d = dl + p * 32;
            uint4 va = *(const uint4*)(A1 + (size_t)(k0 + d) * N_ + n0 + n8);
            const unsigned short* pv = (const unsigned short*)&va;
#pragma unroll
            for (int j = 0; j < 8; ++j) sA1[n8 + j][d] = pv[j];
            uint4 vb = *(const uint4*)(A2 + (size_t)(k0 + d) * N_ + n0 + n8);
            const unsigned short* pw = (const unsigned short*)&vb;
#pragma unroll
            for (int j = 0; j < 8; ++j) sA2[n8 + j][d] = pw[j];
        }
        // stage B row-major: sB[c][d] <- attnp[c0+c][k0+d]
#pragma unroll
        for (int p = 0; p < 4; ++p) {
            int cc = dl + p * 32;
            *(uint4*)&sB1[cc][n8] = *(const uint4*)(B1 + (size_t)cc * 256 + k0 + n8);
            *(uint4*)&sB2[cc][n8] = *(const uint4*)(B2 + (size_t)cc * 256 + k0 + n8);
        }
        __syncthreads();
#pragma unroll
        for (int ksub = 0; ksub < 2; ++ksub) {
            int kc = ksub * 32 + (lane >> 4) * 8;
            bf16x8_t a1f[4], a2f[4], b1f[2], b2f[2];
#pragma unroll
            for (int mi = 0; mi < 4; ++mi) {
                a1f[mi] = *(const bf16x8_t*)&sA1[mi * 16 + (lane & 15)][kc];
                a2f[mi] = *(const bf16x8_t*)&sA2[mi * 16 + (lane & 15)][kc];
            }
#pragma unroll
            for (int ci = 0; ci < 2; ++ci) {
                b1f[ci] = *(const bf16x8_t*)&sB1[wc * 32 + ci * 16 + (lane & 15)][kc];
                b2f[ci] = *(const bf16x8_t*)&sB2[wc * 32 + ci * 16 + (lane & 15)][kc];
            }
#pragma unroll
            for (int mi = 0; mi < 4; ++mi)
#pragma unroll
                for (int ci = 0; ci < 2; ++ci) {
                    acc1[mi][ci] = __builtin_amdgcn_mfma_f32_16x16x32_bf16(a1f[mi], b1f[ci], acc1[mi][ci], 0, 0, 0);
                    acc2[mi][ci] = __builtin_amdgcn_mfma_f32_16x16x32_bf16(a2f[mi], b2f[ci], acc2[mi][ci], 0, 0, 0);
                }
        }
        __syncthreads();
    }

    const size_t obase = (size_t)b * CN_;
    int orow = (lane >> 4) * 4, ocol = lane & 15;
#pragma unroll
    for (int mi = 0; mi < 4; ++mi)
#pragma unroll
        for (int ci = 0; ci < 2; ++ci)
#pragma unroll
            for (int r = 0; r < 4; ++r) {
                int n = n0 + mi * 16 + orow + r;
                int c = c0 + wc * 32 + ci * 16 + ocol;
                size_t f = obase + (size_t)n * 256 + c;
                out[f] = acc1[mi][ci][r] + acc2[mi][ci][r] + x1[f] + x2[f];
            }
}

// --------------------------------- launch ---------------------------------
extern "C" void kernel_launch(void* const* d_in, const int* in_sizes, int n_in,
                              void* d_out, int out_size, void* d_ws, size_t ws_size,
                              hipStream_t stream) {
    const float* x1 = (const float*)d_in[0];
    const float* x2 = (const float*)d_in[1];
    float* out = (float*)d_out;

    char* ws = (char*)d_ws;
    unsigned short* x1n  = (unsigned short*)(ws);                       // 33,554,432 B
    unsigned short* x2n  = (unsigned short*)(ws + 33554432);            // 33,554,432 B
    float*          logits = (float*)(ws + 67108864);                   //  8,388,608 B
    unsigned short* attnp  = (unsigned short*)(ws + 75497472);          //  4,194,304 B
    float*          norms  = (float*)(ws + 79691776);                   //     32,768 B

    knorm<<<4096, 256, 0, stream>>>(x1, x2, x1n, x2n, norms);
    klogits<<<512, 256, 0, stream>>>(x1n, x2n, logits);
    ksoftmax<<<8192, 64, 0, stream>>>(logits, norms, attnp);
    kout<<<2048, 256, 0, stream>>>(x1n, x2n, attnp, x1, x2, out);
}

// Round 2
// 272.586 us; speedup vs baseline: 1.0924x; 1.0924x over previous
//
#include <hip/hip_runtime.h>
#include <hip/hip_bf16.h>

#define B_ 16
#define C_ 256
#define N_ 4096
#define CN_ (C_ * N_)   // 1048576

typedef __attribute__((ext_vector_type(8))) short bf16x8_t;
typedef __attribute__((ext_vector_type(4))) float f32x4_t;
typedef unsigned int u32;
typedef unsigned short u16;

__device__ __forceinline__ u16 f2bf(float f) {
    __hip_bfloat16 h = __float2bfloat16(f);
    return __builtin_bit_cast(u16, h);
}
__device__ __forceinline__ float bf2f(u16 u) {
    return __builtin_bit_cast(float, (u32)u << 16);
}

// async global->LDS, 16B per lane; lds base must be wave-uniform (HW adds lane*16)
__device__ __forceinline__ void gl_lds16(const void* g, void* l) {
    __builtin_amdgcn_global_load_lds(
        (const __attribute__((address_space(1))) u32*)(g),
        (__attribute__((address_space(3))) u32*)(l), 16, 0, 0);
}

// ---------------- kernel 1: norms + bf16 normalize + sums ----------------
__global__ __launch_bounds__(256) void knorm(const float* __restrict__ x1,
                                             const float* __restrict__ x2,
                                             u16* __restrict__ x1n,
                                             u16* __restrict__ x2n,
                                             u16* __restrict__ sN,
                                             u16* __restrict__ sxb,
                                             float* __restrict__ norms) {
    int row = blockIdx.x;              // b*256 + c
    int t = threadIdx.x;
    const float4* r1 = (const float4*)(x1 + (size_t)row * N_);
    const float4* r2 = (const float4*)(x2 + (size_t)row * N_);
    float4 a[4], b[4];
    float s1 = 0.f, s2 = 0.f;
#pragma unroll
    for (int p = 0; p < 4; ++p) {
        a[p] = r1[p * 256 + t];
        b[p] = r2[p * 256 + t];
        s1 += a[p].x * a[p].x + a[p].y * a[p].y + a[p].z * a[p].z + a[p].w * a[p].w;
        s2 += b[p].x * b[p].x + b[p].y * b[p].y + b[p].z * b[p].z + b[p].w * b[p].w;
    }
#pragma unroll
    for (int m = 32; m; m >>= 1) { s1 += __shfl_xor(s1, m); s2 += __shfl_xor(s2, m); }
    __shared__ float red[2][4];
    int wid = t >> 6;
    if ((t & 63) == 0) { red[0][wid] = s1; red[1][wid] = s2; }
    __syncthreads();
    s1 = red[0][0] + red[0][1] + red[0][2] + red[0][3];
    s2 = red[1][0] + red[1][1] + red[1][2] + red[1][3];
    float n1 = fmaxf(sqrtf(s1), 1e-12f);
    float n2 = fmaxf(sqrtf(s2), 1e-12f);
    if (t == 0) {
        int bb = row >> 8, cc = row & 255;
        norms[(bb * 2 + 0) * 256 + cc] = n1;
        norms[(bb * 2 + 1) * 256 + cc] = n2;
    }
    float i1 = 1.0f / n1, i2 = 1.0f / n2;
    u16* o1 = x1n + (size_t)row * N_;
    u16* o2 = x2n + (size_t)row * N_;
    u16* os = sN + (size_t)row * N_;
    u16* or_ = sxb + (size_t)row * N_;
#pragma unroll
    for (int p = 0; p < 4; ++p) {
        ushort4 w1, w2, ws, wr;
        w1.x = f2bf(a[p].x * i1); w1.y = f2bf(a[p].y * i1);
        w1.z = f2bf(a[p].z * i1); w1.w = f2bf(a[p].w * i1);
        w2.x = f2bf(b[p].x * i2); w2.y = f2bf(b[p].y * i2);
        w2.z = f2bf(b[p].z * i2); w2.w = f2bf(b[p].w * i2);
        ws.x = f2bf(a[p].x * i1 + b[p].x * i2); ws.y = f2bf(a[p].y * i1 + b[p].y * i2);
        ws.z = f2bf(a[p].z * i1 + b[p].z * i2); ws.w = f2bf(a[p].w * i1 + b[p].w * i2);
        wr.x = f2bf(a[p].x + b[p].x); wr.y = f2bf(a[p].y + b[p].y);
        wr.z = f2bf(a[p].z + b[p].z); wr.w = f2bf(a[p].w + b[p].w);
        size_t off = (size_t)(p * 256 + t) * 4;
        *(ushort4*)(o1 + off) = w1;
        *(ushort4*)(o2 + off) = w2;
        *(ushort4*)(os + off) = ws;
        *(ushort4*)(or_ + off) = wr;
    }
}

// ------------- kernel 2: logits{w} = sN @ x{w}n^T  (both w fused) ----------
// tile: 64c x 64d, both w per block; 256 blocks; K=4096, BK=64.
__global__ __launch_bounds__(256) void klogits(const u16* __restrict__ sN,
                                               const u16* __restrict__ x1n,
                                               const u16* __restrict__ x2n,
                                               float* __restrict__ logits) {
    int bid = blockIdx.x;                 // 256 blocks
    int xcd = bid & 7;
    int u = bid >> 3;                     // 0..31
    int b = xcd + 8 * (u & 1);
    int tile = u >> 1;                    // 0..15
    int c0 = (tile & 3) * 64;
    int d0 = (tile >> 2) * 64;

    __shared__ u16 lds[3 * 4096];         // 24KB: [0]=sN(c) [1]=x1n(d) [2]=x2n(d)

    int t = threadIdx.x, lane = t & 63, wid = t >> 6;
    int w = wid & 1, chalf = wid >> 1;

    // per-thread staging source bases (byte addrs), k0 added per step
    const char* tb[3];
    tb[0] = (const char*)(sN  + (size_t)b * CN_ + (size_t)c0 * N_);
    tb[1] = (const char*)(x1n + (size_t)b * CN_ + (size_t)d0 * N_);
    tb[2] = (const char*)(x2n + (size_t)b * CN_ + (size_t)d0 * N_);
    const char* gsrc[6];
    char* ldst[6];
#pragma unroll
    for (int qq = 0; qq < 6; ++qq) {
        int q = wid * 6 + qq;             // 0..23 chunks of 1KB
        int ti = q >> 3;
        int s0 = (q & 7) * 1024 + lane * 16;      // byte within tile
        int rrow = s0 >> 7, inner = s0 & 127;
        gsrc[qq] = tb[ti] + (size_t)rrow * (N_ * 2) + (inner ^ ((rrow & 7) << 4));
        ldst[qq] = (char*)lds + q * 1024;
    }

    f32x4_t acc[2][4];
#pragma unroll
    for (int i = 0; i < 2; ++i)
#pragma unroll
        for (int j = 0; j < 4; ++j) acc[i][j] = 0.f;

    const char* Abase = (const char*)lds;                 // sN tile
    const char* Bbase = (const char*)(lds + (1 + w) * 4096);
    int kl = (lane >> 4) * 16;            // byte offset within 128B row
    int rA0 = chalf * 32 + (lane & 15);

    for (int ks = 0; ks < 64; ++ks) {
        int kbyte = ks * 128;
#pragma unroll
        for (int qq = 0; qq < 6; ++qq)
            gl_lds16(gsrc[qq] + kbyte, ldst[qq]);
        __syncthreads();
#pragma unroll
        for (int ksub = 0; ksub < 2; ++ksub) {
            int kc = ksub * 64 + kl;
            bf16x8_t af[2], bfr[4];
#pragma unroll
            for (int mi = 0; mi < 2; ++mi) {
                int rr = rA0 + mi * 16;
                af[mi] = *(const bf16x8_t*)(Abase + ((rr << 7) + (kc ^ ((rr & 7) << 4))));
            }
#pragma unroll
            for (int ni = 0; ni < 4; ++ni) {
                int rr = ni * 16 + (lane & 15);
                bfr[ni] = *(const bf16x8_t*)(Bbase + ((rr << 7) + (kc ^ ((rr & 7) << 4))));
            }
#pragma unroll
            for (int mi = 0; mi < 2; ++mi)
#pragma unroll
                for (int ni = 0; ni < 4; ++ni)
                    acc[mi][ni] = __builtin_amdgcn_mfma_f32_16x16x32_bf16(af[mi], bfr[ni], acc[mi][ni], 0, 0, 0);
        }
        __syncthreads();
    }

    float* outp = logits + ((size_t)((b * 2 + w) * 256 + c0 + chalf * 32)) * 256 + d0;
    int orow = (lane >> 4) * 4, ocol = lane & 15;
#pragma unroll
    for (int mi = 0; mi < 2; ++mi)
#pragma unroll
        for (int ni = 0; ni < 4; ++ni)
#pragma unroll
            for (int r = 0; r < 4; ++r)
                outp[(size_t)(mi * 16 + orow + r) * 256 + ni * 16 + ocol] = acc[mi][ni][r];
}

// ------------- kernel 3: row softmax + fold norm[d], emit bf16 ------------
__global__ __launch_bounds__(256) void ksoftmax(const float* __restrict__ logits,
                                                const float* __restrict__ norms,
                                                u16* __restrict__ attnp) {
    int rid = blockIdx.x * 4 + (threadIdx.x >> 6);   // (b*2+w)*256 + c
    int l = threadIdx.x & 63;
    const float* row = logits + (size_t)rid * 256;
    int bw = rid >> 8;
    float v[4];
    float m = -1e30f;
#pragma unroll
    for (int j = 0; j < 4; ++j) { v[j] = row[j * 64 + l]; m = fmaxf(m, v[j]); }
#pragma unroll
    for (int s = 32; s; s >>= 1) m = fmaxf(m, __shfl_xor(m, s));
    float sum = 0.f;
#pragma unroll
    for (int j = 0; j < 4; ++j) { v[j] = __expf(v[j] - m); sum += v[j]; }
#pragma unroll
    for (int s = 32; s; s >>= 1) sum += __shfl_xor(sum, s);
    float rs = 1.0f / sum;
    u16* outp = attnp + (size_t)rid * 256;
    const float* nr = norms + (size_t)bw * 256;
#pragma unroll
    for (int j = 0; j < 4; ++j)
        outp[j * 64 + l] = f2bf(v[j] * rs * nr[j * 64 + l]);
}

// ------- kernel 4: out[n,c] = yT1 + yT2 + (x1+x2) (fused both which) ------
// A (64n x 64d per step) built by register pack-4 transpose from x{w}n rows;
// B (128c x 64d) via global_load_lds; both XOR-swizzled; K=256, 4 steps.
__global__ __launch_bounds__(256) void kout(const u16* __restrict__ x1n,
                                            const u16* __restrict__ x2n,
                                            const u16* __restrict__ attnp,
                                            const u16* __restrict__ sxb,
                                            float* __restrict__ out) {
    int bid = blockIdx.x;              // 2048 blocks
    int xcd = bid & 7;
    int u = bid >> 3;                  // 0..255
    int b = xcd + 8 * (u & 1);
    int rest = u >> 1;                 // 0..127
    int n0 = (rest >> 1) * 64;
    int c0 = (rest & 1) * 128;

    __shared__ u16 sA[2][4096];        // 8KB each: [n(64)][d(64)] swizzled
    __shared__ u16 sB[2][8192];        // 16KB each: [c(128)][d(64)] swizzled

    int t = threadIdx.x, lane = t & 63, wid = t >> 6;
    int wc = wid;                      // 32-wide c slice per wave

    // A staging assignment: 2 waves per tensor
    int tensorA = t >> 7;              // 0: x1n, 1: x2n
    int tt = t & 127;
    int dq = (tt & 15) * 4;            // 4 consecutive d rows
    int n8 = (tt >> 4) * 8;            // 8 consecutive n cols
    const u16* Asrc = (tensorA ? x2n : x1n) + (size_t)b * CN_ + n0 + n8;
    char* sAme = (char*)&sA[tensorA][0];

    // B staging: 32 chunks of 1KB, wave wid handles 8
    const char* gB[8];
    char* lB[8];
#pragma unroll
    for (int qq = 0; qq < 8; ++qq) {
        int q = wid * 8 + qq;
        int tensor = q >> 4;
        int s0 = (q & 15) * 1024 + lane * 16;
        int rrow = s0 >> 7, inner = s0 & 127;
        gB[qq] = (const char*)attnp +
                 ((size_t)((b * 2 + tensor) * 256 + c0 + rrow) * 256) * 2 +
                 (inner ^ ((rrow & 7) << 4));
        lB[qq] = (char*)&sB[0][0] + q * 1024;
    }

    f32x4_t acc1[4][2], acc2[4][2];
#pragma unroll
    for (int i = 0; i < 4; ++i)
#pragma unroll
        for (int j = 0; j < 2; ++j) { acc1[i][j] = 0.f; acc2[i][j] = 0.f; }

    int kl = (lane >> 4) * 16;
    const char* A0 = (const char*)&sA[0][0];
    const char* A1 = (const char*)&sA[1][0];
    const char* B0 = (const char*)&sB[0][0];
    const char* B1 = (const char*)&sB[1][0];

    for (int ks = 0; ks < 4; ++ks) {
        int k0 = ks * 64;
        // ---- B via async gload_lds (pre-swizzled source) ----
#pragma unroll
        for (int qq = 0; qq < 8; ++qq)
            gl_lds16(gB[qq] + k0 * 2, lB[qq]);
        // ---- A via register pack-4 transpose ----
        uint4 r0 = *(const uint4*)(Asrc + (size_t)(k0 + dq + 0) * N_);
        uint4 r1 = *(const uint4*)(Asrc + (size_t)(k0 + dq + 1) * N_);
        uint4 r2 = *(const uint4*)(Asrc + (size_t)(k0 + dq + 2) * N_);
        uint4 r3 = *(const uint4*)(Asrc + (size_t)(k0 + dq + 3) * N_);
        const u16* p0 = (const u16*)&r0;
        const u16* p1 = (const u16*)&r1;
        const u16* p2 = (const u16*)&r2;
        const u16* p3 = (const u16*)&r3;
#pragma unroll
        for (int i = 0; i < 8; ++i) {
            u32 lo = (u32)p0[i] | ((u32)p1[i] << 16);
            u32 hi = (u32)p2[i] | ((u32)p3[i] << 16);
            int n = n8 + i;
            int addr = (n << 7) + (((dq << 1)) ^ ((n & 7) << 4));
            uint2 val; val.x = lo; val.y = hi;
            *(uint2*)(sAme + addr) = val;
        }
        __syncthreads();
#pragma unroll
        for (int ksub = 0; ksub < 2; ++ksub) {
            int kc = ksub * 64 + kl;
            bf16x8_t a1f[4], a2f[4], b1f[2], b2f[2];
#pragma unroll
            for (int mi = 0; mi < 4; ++mi) {
                int rr = mi * 16 + (lane & 15);
                int ao = (rr << 7) + (kc ^ ((rr & 7) << 4));
                a1f[mi] = *(const bf16x8_t*)(A0 + ao);
                a2f[mi] = *(const bf16x8_t*)(A1 + ao);
            }
#pragma unroll
            for (int ci = 0; ci < 2; ++ci) {
                int rr = wc * 32 + ci * 16 + (lane & 15);
                int bo = (rr << 7) + (kc ^ ((rr & 7) << 4));
                b1f[ci] = *(const bf16x8_t*)(B0 + bo);
                b2f[ci] = *(const bf16x8_t*)(B1 + bo);
            }
#pragma unroll
            for (int mi = 0; mi < 4; ++mi)
#pragma unroll
                for (int ci = 0; ci < 2; ++ci) {
                    acc1[mi][ci] = __builtin_amdgcn_mfma_f32_16x16x32_bf16(a1f[mi], b1f[ci], acc1[mi][ci], 0, 0, 0);
                    acc2[mi][ci] = __builtin_amdgcn_mfma_f32_16x16x32_bf16(a2f[mi], b2f[ci], acc2[mi][ci], 0, 0, 0);
                }
        }
        __syncthreads();
    }

    const size_t obase = (size_t)b * CN_;
    int orow = (lane >> 4) * 4, ocol = lane & 15;
#pragma unroll
    for (int mi = 0; mi < 4; ++mi)
#pragma unroll
        for (int ci = 0; ci < 2; ++ci)
#pragma unroll
            for (int r = 0; r < 4; ++r) {
                int n = n0 + mi * 16 + orow + r;
                int c = c0 + wc * 32 + ci * 16 + ocol;
                size_t f = obase + (size_t)n * 256 + c;
                out[f] = acc1[mi][ci][r] + acc2[mi][ci][r] + bf2f(sxb[f]);
            }
}

// --------------------------------- launch ---------------------------------
extern "C" void kernel_launch(void* const* d_in, const int* in_sizes, int n_in,
                              void* d_out, int out_size, void* d_ws, size_t ws_size,
                              hipStream_t stream) {
    const float* x1 = (const float*)d_in[0];
    const float* x2 = (const float*)d_in[1];
    float* out = (float*)d_out;

    char* ws = (char*)d_ws;
    u16*   x1n    = (u16*)(ws);                        // 32 MB
    u16*   x2n    = (u16*)(ws + 33554432ull);          // 32 MB
    u16*   sN     = (u16*)(ws + 67108864ull);          // 32 MB
    u16*   sxb    = (u16*)(ws + 100663296ull);         // 32 MB
    float* logits = (float*)(ws + 134217728ull);       //  8 MB
    u16*   attnp  = (u16*)(ws + 142606336ull);         //  4 MB
    float* norms  = (float*)(ws + 146800640ull);       // 32 KB

    knorm<<<4096, 256, 0, stream>>>(x1, x2, x1n, x2n, sN, sxb, norms);
    klogits<<<256, 256, 0, stream>>>(sN, x1n, x2n, logits);
    ksoftmax<<<2048, 256, 0, stream>>>(logits, norms, attnp);
    kout<<<2048, 256, 0, stream>>>(x1n, x2n, attnp, sxb, out);
}